// Round 5
// baseline (2072.966 us; speedup 1.0000x reference)
//
#include <hip/hip_runtime.h>
#include <hip/hip_cooperative_groups.h>
#include <math.h>

namespace cg = cooperative_groups;

// Problem constants (reference: B,N,M,C = 4,4096,4096,256)
#define BB 4
#define BN 4096          // N == M == 4096
#define CC 256
constexpr float T2      = 0.04f;                     // DIST_THRESH^2
constexpr float NEGINF  = -1.0e9f;
constexpr float INV_EPS = (float)(1.0 / 0.01000001); // 1/(EPSILON + 1e-8)

__device__ __forceinline__ int cell_of(float x, float y) {
  int cx = (int)(x * 5.0f); cx = cx < 0 ? 0 : (cx > 4 ? 4 : cx);
  int cy = (int)(y * 5.0f); cy = cy < 0 ? 0 : (cy > 4 ? 4 : cy);
  return cy * 5 + cx;
}

// ------------------------------------------------------ sparse Sinkhorn -----
// (body identical to the verified round-4 k_sink; see its comment block)
// 4 rows per wave, plain-sum. Union-box over-scan is masked by d2 < T2.
// Leak terms folded via per-batch Z count; empty rows -> exactly 1e9f.
__device__ static void sink_pass(const float4* __restrict__ opp,
                                 float4* __restrict__ own,
                                 const int* __restrict__ opp_starts,
                                 const int* __restrict__ Zin,
                                 int* __restrict__ Zout,
                                 int zero_invalid) {
  const int wv   = threadIdx.x >> 6;            // wave 0..3
  const int lane = threadIdx.x & 63;
  const int rowb = blockIdx.x * 16 + wv * 4;    // 4 rows/wave; 1024 blocks exact
  const int b    = rowb >> 12;                  // batch (no group crosses batch)
  float4 me[4];
  float  s[4] = {0.f, 0.f, 0.f, 0.f};
  int ryLo = 5, ryHi = -1, rxLo = 5, rxHi = -1;
  #pragma unroll
  for (int i = 0; i < 4; i++) {
    me[i] = own[rowb + i];
    if (me[i].w != 0.f) {                        // invalid rows: no finite terms
      int cell = cell_of(me[i].x, me[i].y);
      int cy = cell / 5, cx = cell % 5;
      ryLo = min(ryLo, max(cy - 1, 0)); ryHi = max(ryHi, min(cy + 1, 4));
      rxLo = min(rxLo, max(cx - 1, 0)); rxHi = max(rxHi, min(cx + 1, 4));
    }
  }
  for (int ry = ryLo; ry <= ryHi; ry++) {
    const int r0 = opp_starts[b * 32 + ry * 5 + rxLo];
    const int r1 = opp_starts[b * 32 + ry * 5 + rxHi + 1];  // contiguous cells
    for (int j = r0 + lane; j < r1; j += 64) {
      float4 o = opp[b * BN + j];
      #pragma unroll
      for (int i = 0; i < 4; i++) {
        float dx = me[i].x - o.x, dy = me[i].y - o.y;
        float d2 = fmaf(dx, dx, dy * dy);
        bool  c  = (d2 < T2) && (o.w != 0.f) && (me[i].w != 0.f);
        float t  = c ? fmaf(d2, -INV_EPS, o.z) : -3e30f;    // masked: exp -> 0
        s[i] += __expf(t);
      }
    }
  }
  #pragma unroll
  for (int i = 0; i < 4; i++)
    for (int off = 32; off > 0; off >>= 1) s[i] += __shfl_xor(s[i], off);
  if (lane == 0) {
    const float Zf = (float)Zin[b];
    #pragma unroll
    for (int i = 0; i < 4; i++) {
      float ss  = s[i] + Zf;                     // leak terms: exp(0)=1, Z of them
      float val = (ss > 0.f) ? -logf(ss) : 1.0e9f;  // empty row -> exactly 1e9f
      if (zero_invalid && me[i].w == 0.f) val = 0.f;
      own[rowb + i] = make_float4(me[i].x, me[i].y, val, me[i].w);
      if (val == 1.0e9f) atomicAdd(&Zout[b], 1);
    }
  }
}

// ------------------------------------------- fused prep + Sinkhorn (coop) ---
// One cooperative kernel replaces: ws memset, k_count, k_scan_scatter and the
// six serial k_sink dispatches (11 -> 3 dispatches per iteration). Phase
// bodies are byte-identical to the previously verified kernels; phases are
// separated by __threadfence() (device-scope visibility across XCDs, G16)
// + grid.sync(). 1024 blocks x 256 thr = 4 blocks/CU -> co-residency holds.
__global__ __launch_bounds__(256) void k_fused(
    const float* __restrict__ tlocs, const float* __restrict__ slocs,
    const int* __restrict__ tmask, const int* __restrict__ smask,
    int* __restrict__ wsi,                  // counts_t[128] counts_s[128] Zc[...]
    int* __restrict__ starts_t, int* __restrict__ starts_s,
    int* __restrict__ perm_t, int* __restrict__ perm_s,
    float4* __restrict__ t_sorted, float4* __restrict__ s_sorted) {
  cg::grid_group grid = cg::this_grid();
  int* counts_t = wsi;                      // ws layout unchanged vs host version
  int* counts_s = wsi + 128;
  int* Zc       = wsi + 256;
  const int tid  = threadIdx.x;
  const int gtid = blockIdx.x * 256 + tid;

  // ---- phase 0: zero cell + Z counters (2048 B) ----------------------------
  if (gtid < 512) wsi[gtid] = 0;
  __threadfence();
  grid.sync();

  // ---- phase 1: per-cell counts (ex k_count) -------------------------------
  if (gtid < 2 * BB * BN) {
    if (gtid < BB * BN) {
      int b = gtid >> 12;
      atomicAdd(&counts_t[b * 32 + cell_of(tlocs[gtid * 2], tlocs[gtid * 2 + 1])], 1);
    } else {
      int g = gtid - BB * BN;
      int b = g >> 12;
      atomicAdd(&counts_s[b * 32 + cell_of(slocs[g * 2], slocs[g * 2 + 1])], 1);
    }
  }
  __threadfence();
  grid.sync();

  // ---- phase 2: scan 25 cells + scatter packs (ex k_scan_scatter, blocks 0..7)
  __shared__ int st[26];
  __shared__ int cur[25];
  if (blockIdx.x < 8) {
    const int which = blockIdx.x & 1, b = blockIdx.x >> 1;
    const float* locs = which ? slocs : tlocs;
    const int*   mask = which ? smask : tmask;
    const int* counts = which ? counts_s : counts_t;
    int* starts       = which ? starts_s : starts_t;
    int* perm         = which ? perm_s : perm_t;
    float4* pack      = which ? s_sorted : t_sorted;
    if (tid == 0) {
      int acc = 0;
      for (int c = 0; c < 25; c++) { st[c] = acc; acc += counts[b * 32 + c]; }
      st[25] = acc;                                   // == 4096
    }
    __syncthreads();
    if (tid < 25) cur[tid] = st[tid];
    if (tid < 26) starts[b * 32 + tid] = st[tid];
    __syncthreads();
    for (int i = tid; i < BN; i += 256) {
      float x = locs[(b * BN + i) * 2], y = locs[(b * BN + i) * 2 + 1];
      int pos = atomicAdd(&cur[cell_of(x, y)], 1);
      perm[b * BN + pos] = i;
      pack[b * BN + pos] = make_float4(x, y, 0.f, mask[b * BN + i] ? 1.f : 0.f);
    }
  }
  __threadfence();
  grid.sync();

  // ---- phases 3..8: six Sinkhorn half-iterations ---------------------------
  for (int it = 0; it < 3; it++) {
    // u-update: Zin = leak count of current v (slot 0 = zeros for it==0)
    sink_pass(s_sorted, t_sorted, starts_s,
              Zc + (it == 0 ? 0 : (2 * it) * 4), Zc + (2 * it + 1) * 4, 0);
    __threadfence();
    grid.sync();
    // v-update: Zin = leak count of u just written
    sink_pass(t_sorted, s_sorted, starts_t,
              Zc + (2 * it + 1) * 4, Zc + (2 * it + 2) * 4, 1);
    __threadfence();
    grid.sync();
  }
}

// ------------------------------------------------- sparse attn @ feats ------
// UNCHANGED (verified 281 us). Block = (batch, cell, box-row, 32-target
// chunk). Partials across the 3 box-rows combine with atomicAdd (out zeroed
// first). Gates redundant: attn computed as exactly 0 wherever the reference
// gates would zero out.
#define MAXCH 12   // 12*32 = 384 targets/cell upper bound (mean 164, sigma 12.5)

__global__ __launch_bounds__(256) void k_out(
    const float* __restrict__ feats, const float4* __restrict__ t_sorted,
    const float4* __restrict__ s_sorted, const int* __restrict__ perm_t,
    const int* __restrict__ perm_s, const int* __restrict__ starts_t,
    const int* __restrict__ starts_s, float* __restrict__ out) {
  const int b = blockIdx.z;
  const int cell = blockIdx.y / 3, rsel = blockIdx.y % 3;
  const int cy = cell / 5, cx = cell % 5;
  const int ry = cy + rsel - 1;
  if (ry < 0 || ry > 4) return;                            // uniform early-exit
  const int t0 = starts_t[b * 32 + cell], t1 = starts_t[b * 32 + cell + 1];
  const int base = t0 + blockIdx.x * 32;
  if (base >= t1) return;
  const int rx0 = max(cx - 1, 0), rx1 = min(cx + 1, 4);
  const int s0 = starts_s[b * 32 + ry * 5 + rx0];
  const int s1 = starts_s[b * 32 + ry * 5 + rx1 + 1];
  if (s0 >= s1) return;
  const int nt = min(32, t1 - base);

  __shared__ float4 tL[32];                // x, y, u, tv
  __shared__ int    morg[32];
  __shared__ float4 sL[16];                // x, y, v, sv
  __shared__ int    sorg[16];
  __shared__ __align__(16) float attnL[16][32];
  __shared__ __align__(16) float fL[16 * 256];

  const int tid = threadIdx.x;
  if (tid < 32) {
    if (tid < nt) {
      tL[tid]   = t_sorted[b * BN + base + tid];
      morg[tid] = perm_t[b * BN + base + tid];
    } else {
      tL[tid]   = make_float4(0.f, 0.f, 0.f, 0.f);         // tv=0 -> attn 0
      morg[tid] = 0;
    }
  }
  const int tmg = tid >> 5;                // 0..7  -> targets tmg*4 .. +3
  const int chg = tid & 31;                // channels chg*4..+3 and +128
  float acc[4][8];
  #pragma unroll
  for (int i = 0; i < 4; i++)
    #pragma unroll
    for (int j = 0; j < 8; j++) acc[i][j] = 0.f;
  __syncthreads();

  for (int n0 = s0; n0 < s1; n0 += 16) {
    const int kk = min(16, s1 - n0);
    __syncthreads();                       // previous MAC done before restaging
    if (tid < 16) {
      if (tid < kk) {
        sL[tid]   = s_sorted[b * BN + n0 + tid];
        sorg[tid] = perm_s[b * BN + n0 + tid];
      } else {
        sL[tid]   = make_float4(1e9f, 1e9f, 0.f, 0.f);     // pad: attn==0
        sorg[tid] = 0;
      }
    }
    __syncthreads();
    {                                      // attn tile: 512 entries, 2/thread
      int e = tid * 2;
      #pragma unroll
      for (int q = 0; q < 2; q++, e++) {
        int nn = e >> 5, tm = e & 31;
        float4 t4 = tL[tm];
        float4 s4 = sL[nn];
        float dx = t4.x - s4.x, dy = t4.y - s4.y;
        float d2 = fmaf(dx, dx, dy * dy);
        bool  c  = (d2 < T2) && (s4.w != 0.f) && (t4.w != 0.f);
        attnL[nn][tm] = c ? __expf(fmaf(d2, -INV_EPS, t4.z + s4.z)) : 0.f;
      }
    }
    #pragma unroll                         // feats tile: 4 x dwordx4 per thread
    for (int q = 0; q < 4; q++) {
      int idx = q * 256 + tid;             // fL as float4[1024]: row = idx>>6
      ((float4*)fL)[idx] =
          ((const float4*)feats)[(((b << 12) + sorg[idx >> 6]) << 6) + (idx & 63)];
    }
    __syncthreads();
    #pragma unroll 4                       // MAC: 3 ds_read_b128 per 32 FMA
    for (int nn = 0; nn < 16; nn++) {
      const float4 av = *(const float4*)&attnL[nn][tmg * 4];
      const float4 f0 = *(const float4*)&fL[nn * 256 + chg * 4];
      const float4 f1 = *(const float4*)&fL[nn * 256 + 128 + chg * 4];
      float avv[4] = {av.x, av.y, av.z, av.w};
      float ff[8]  = {f0.x, f0.y, f0.z, f0.w, f1.x, f1.y, f1.z, f1.w};
      #pragma unroll
      for (int i = 0; i < 4; i++)
        #pragma unroll
        for (int j = 0; j < 8; j++)
          acc[i][j] = fmaf(avv[i], ff[j], acc[i][j]);
    }
  }
  __syncthreads();
  #pragma unroll
  for (int i = 0; i < 4; i++) {
    int tm = tmg * 4 + i;
    if (tm < nt) {
      float* op = out + (((b << 12) + morg[tm]) << 8) + chg * 4;
      #pragma unroll
      for (int j = 0; j < 4; j++) atomicAdd(op + j,       acc[i][j]);
      #pragma unroll
      for (int j = 0; j < 4; j++) atomicAdd(op + 128 + j, acc[i][j + 4]);
    }
  }
}

// ----------------------------------------------------------------- launch ---
extern "C" void kernel_launch(void* const* d_in, const int* in_sizes, int n_in,
                              void* d_out, int out_size, void* d_ws, size_t ws_size,
                              hipStream_t stream) {
  const float* feats = (const float*)d_in[0];   // [B,N,C] f32
  const float* slocs = (const float*)d_in[1];   // [B,N,2] f32
  const float* tlocs = (const float*)d_in[2];   // [B,M,2] f32
  const int*   smask = (const int*)d_in[3];     // [B,N] int32 (bool)
  const int*   tmask = (const int*)d_in[4];     // [B,M] int32 (bool)
  float* out = (float*)d_out;

  char* ws = (char*)d_ws;                       // ~660 KB used
  int*    wsi      = (int*)(ws);                // counts_t @0, counts_s @512, Zc @1024
  int*    starts_t = (int*)(ws + 2048);         //   512 B
  int*    starts_s = (int*)(ws + 2560);         //   512 B
  int*    perm_t   = (int*)(ws + 4096);         //   64 KB
  int*    perm_s   = (int*)(ws + 69632);        //   64 KB
  float4* s_sorted = (float4*)(ws + 135168);    //  256 KB (x,y,v,sv) cell-sorted
  float4* t_sorted = (float4*)(ws + 397312);    //  256 KB (x,y,u,tv) cell-sorted

  hipMemsetAsync(out, 0, (size_t)out_size * sizeof(float), stream);

  void* kargs[] = {(void*)&tlocs, (void*)&slocs, (void*)&tmask, (void*)&smask,
                   (void*)&wsi, (void*)&starts_t, (void*)&starts_s,
                   (void*)&perm_t, (void*)&perm_s,
                   (void*)&t_sorted, (void*)&s_sorted};
  hipLaunchCooperativeKernel(k_fused, dim3(1024), dim3(256), kargs, 0, stream);

  k_out<<<dim3(MAXCH, 75, BB), 256, 0, stream>>>(feats, t_sorted, s_sorted,
                                                 perm_t, perm_s, starts_t,
                                                 starts_s, out);
}

// Round 6
// 572.424 us; speedup vs baseline: 3.6214x; 3.6214x over previous
//
#include <hip/hip_runtime.h>
#include <math.h>

// Problem constants (reference: B,N,M,C = 4,4096,4096,256)
#define BB 4
#define BN 4096          // N == M == 4096
#define CC 256
constexpr float T2      = 0.04f;                     // DIST_THRESH^2
constexpr float INV_EPS = (float)(1.0 / 0.01000001); // 1/(EPSILON + 1e-8)

__device__ __forceinline__ int cell_of(float x, float y) {
  int cx = (int)(x * 5.0f); cx = cx < 0 ? 0 : (cx > 4 ? 4 : cx);
  int cy = (int)(y * 5.0f); cy = cy < 0 ? 0 : (cy > 4 ? 4 : cy);
  return cy * 5 + cx;
}

// async 16B/lane global->LDS DMA: LDS dest = wave-uniform base + lane*16.
__device__ __forceinline__ void dma16(const void* g, void* l) {
  __builtin_amdgcn_global_load_lds(
      (const __attribute__((address_space(1))) void*)g,
      (__attribute__((address_space(3))) void*)l, 16, 0, 0);
}

// ------------------------------------------------- fused binning (8 blk) ----
// Per-(side,batch) block: count its own 4096 points into LDS, scan 25 cells,
// scatter perm + cell-sorted packs. Replaces ws-memset + k_count +
// k_scan_scatter (block-local counts -> no cross-block dependency). Block 0
// also zeroes the Zc leak counters (ws+1024..2048).
__global__ __launch_bounds__(256) void k_bin(
    const float* __restrict__ tlocs, const float* __restrict__ slocs,
    const int* __restrict__ tmask, const int* __restrict__ smask,
    int* __restrict__ Zc,
    int* __restrict__ starts_t, int* __restrict__ starts_s,
    int* __restrict__ perm_t, int* __restrict__ perm_s,
    float4* __restrict__ t_sorted, float4* __restrict__ s_sorted) {
  const int which = blockIdx.x & 1, b = blockIdx.x >> 1;   // grid = 2*B
  const float* locs = which ? slocs : tlocs;
  const int*   mask = which ? smask : tmask;
  int* starts       = which ? starts_s : starts_t;
  int* perm         = which ? perm_s : perm_t;
  float4* pack      = which ? s_sorted : t_sorted;
  const int tid = threadIdx.x;
  if (blockIdx.x == 0) Zc[tid] = 0;                        // 256 ints = 1 KB
  __shared__ int cnt[25];
  __shared__ int st[26];
  __shared__ int cur[25];
  if (tid < 25) cnt[tid] = 0;
  __syncthreads();
  for (int i = tid; i < BN; i += 256)
    atomicAdd(&cnt[cell_of(locs[(b * BN + i) * 2], locs[(b * BN + i) * 2 + 1])], 1);
  __syncthreads();
  if (tid == 0) {
    int acc = 0;
    for (int c = 0; c < 25; c++) { st[c] = acc; acc += cnt[c]; }
    st[25] = acc;                                          // == 4096
  }
  __syncthreads();
  if (tid < 25) cur[tid] = st[tid];
  if (tid < 26) starts[b * 32 + tid] = st[tid];
  __syncthreads();
  for (int i = tid; i < BN; i += 256) {
    float x = locs[(b * BN + i) * 2], y = locs[(b * BN + i) * 2 + 1];
    int pos = atomicAdd(&cur[cell_of(x, y)], 1);
    perm[b * BN + pos] = i;
    pack[b * BN + pos] = make_float4(x, y, 0.f, mask[b * BN + i] ? 1.f : 0.f);
  }
}

// ------------------------------------------------------ sparse Sinkhorn -----
// r4-verified. 4 rows per wave, plain-sum (no online max): finite terms
// t = logK + opp.z are bounded (|z| <~ 65 worst case) -> sum(exp) can't
// overflow f32; masked terms t=-3e30 -> __expf == exactly 0. Leak terms
// (exp(0)=1 each) folded via per-batch Z count; empty rows -> exactly 1e9f
// (same as dense: -1e9 + log(count) rounds back to -1e9). Union-box over-scan
// is masked by d2 < T2. zero_invalid mirrors v = where(source_valid, v, 0).
__global__ __launch_bounds__(256) void k_sink(const float4* __restrict__ opp,
                                              float4* __restrict__ own,
                                              const int* __restrict__ opp_starts,
                                              const int* __restrict__ Zin,
                                              int* __restrict__ Zout,
                                              int zero_invalid) {
  const int wv   = threadIdx.x >> 6;            // wave 0..3
  const int lane = threadIdx.x & 63;
  const int rowb = blockIdx.x * 16 + wv * 4;    // 4 rows/wave; 1024 blocks exact
  const int b    = rowb >> 12;                  // batch (no group crosses batch)
  float4 me[4];
  float  s[4] = {0.f, 0.f, 0.f, 0.f};
  int ryLo = 5, ryHi = -1, rxLo = 5, rxHi = -1;
  #pragma unroll
  for (int i = 0; i < 4; i++) {
    me[i] = own[rowb + i];
    if (me[i].w != 0.f) {                        // invalid rows: no finite terms
      int cell = cell_of(me[i].x, me[i].y);
      int cy = cell / 5, cx = cell % 5;
      ryLo = min(ryLo, max(cy - 1, 0)); ryHi = max(ryHi, min(cy + 1, 4));
      rxLo = min(rxLo, max(cx - 1, 0)); rxHi = max(rxHi, min(cx + 1, 4));
    }
  }
  for (int ry = ryLo; ry <= ryHi; ry++) {
    const int r0 = opp_starts[b * 32 + ry * 5 + rxLo];
    const int r1 = opp_starts[b * 32 + ry * 5 + rxHi + 1];  // contiguous cells
    for (int j = r0 + lane; j < r1; j += 64) {
      float4 o = opp[b * BN + j];
      #pragma unroll
      for (int i = 0; i < 4; i++) {
        float dx = me[i].x - o.x, dy = me[i].y - o.y;
        float d2 = fmaf(dx, dx, dy * dy);
        bool  c  = (d2 < T2) && (o.w != 0.f) && (me[i].w != 0.f);
        float t  = c ? fmaf(d2, -INV_EPS, o.z) : -3e30f;    // masked: exp -> 0
        s[i] += __expf(t);
      }
    }
  }
  #pragma unroll
  for (int i = 0; i < 4; i++)
    for (int off = 32; off > 0; off >>= 1) s[i] += __shfl_xor(s[i], off);
  if (lane == 0) {
    const float Zf = (float)Zin[b];
    #pragma unroll
    for (int i = 0; i < 4; i++) {
      float ss  = s[i] + Zf;                     // leak terms: exp(0)=1, Z of them
      float val = (ss > 0.f) ? -logf(ss) : 1.0e9f;  // empty row -> exactly 1e9f
      if (zero_invalid && me[i].w == 0.f) val = 0.f;
      own[rowb + i] = make_float4(me[i].x, me[i].y, val, me[i].w);
      if (val == 1.0e9f) atomicAdd(&Zout[b], 1);
    }
  }
}

// ------------------------------------------------- sparse attn @ feats ------
// DMA double-buffered rewrite of the verified scalar-FMA kernel.
// Per 16-source round (ONE raw barrier, no vmcnt-0-inside-compute):
//   [vmcnt(0); s_barrier; sched_barrier] -> all waves' DMA(k) landed, all
//   waves done reading buf[k-1].
//   issue DMA(k+1) -> fL[buf^1] (4 x global_load_lds per wave = 4 rows),
//   prefetch s_sorted rows (k+1) + perm_s idx (k+2) into regs,
//   attn(k): WAVE-LOCAL (wave w computes cols w*8..w*8+7 it alone consumes;
//   same-wave ds ordering via lgkmcnt, no barrier), MAC(k) from fL[buf].
// DMA latency hides under the ~1024-cyc MAC; the top-of-round vmcnt(0) is
// then ~free. Hazard: DMA(k+1) overwrites buf read by MAC(k-1) -- excluded
// because passing round-k's barrier implies all waves finished MAC(k-1).
#define MAXCH 12   // 12*32 = 384 targets/cell upper bound
#define CH 16      // sources per round

__global__ __launch_bounds__(256) void k_out(
    const float* __restrict__ feats, const float4* __restrict__ t_sorted,
    const float4* __restrict__ s_sorted, const int* __restrict__ perm_t,
    const int* __restrict__ perm_s, const int* __restrict__ starts_t,
    const int* __restrict__ starts_s, float* __restrict__ out) {
  const int b = blockIdx.z;
  const int cell = blockIdx.y / 3, rsel = blockIdx.y % 3;
  const int cy = cell / 5, cx = cell % 5;
  const int ry = cy + rsel - 1;
  if (ry < 0 || ry > 4) return;                            // uniform early-exit
  const int t0 = starts_t[b * 32 + cell], t1 = starts_t[b * 32 + cell + 1];
  const int base = t0 + blockIdx.x * 32;
  if (base >= t1) return;
  const int rx0 = max(cx - 1, 0), rx1 = min(cx + 1, 4);
  const int s0 = starts_s[b * 32 + ry * 5 + rx0];
  const int s1 = starts_s[b * 32 + ry * 5 + rx1 + 1];
  if (s0 >= s1) return;
  const int nt = min(32, t1 - base);

  __shared__ float4 tL[32];                    // x, y, u, tv
  __shared__ int    morg[32];
  __shared__ __align__(16) float attnL[16 * 36];   // stride 36: bank-spread, 16B rows
  __shared__ __align__(16) float fL[2 * CH * 256]; // 32 KB double-buffered feats

  const int tid  = threadIdx.x;
  const int lane = tid & 63;
  const int w    = tid >> 6;                   // wave 0..3

  if (tid < 32) {
    if (tid < nt) {
      tL[tid]   = t_sorted[b * BN + base + tid];
      morg[tid] = perm_t[b * BN + base + tid];
    } else {
      tL[tid]   = make_float4(0.f, 0.f, 0.f, 0.f);         // tv=0 -> attn 0
      morg[tid] = 0;
    }
  }
  __syncthreads();

  const int tmg  = tid >> 5;                   // consumer: targets tmg*4..+3
  const int chg  = tid & 31;                   // consumer: channels chg*4..+3,+128
  const int tmp_ = w * 8 + (lane & 7);         // producer: attn column (wave-local)
  const int nnA  = lane >> 3, nnB = nnA + 8;   // producer: attn rows
  const float4 t4p = tL[tmp_];                 // hoisted target row (regs)
  const int sB = b * BN;

  // ---- prologue: round-0 prefetches + DMA(0) into buf 0 --------------------
  float4 psA = s_sorted[sB + min(s0 + nnA, s1 - 1)];
  float4 psB = s_sorted[sB + min(s0 + nnB, s1 - 1)];
  float4 pnA, pnB;
  int sidxN[4];
  {
    int s0i[4];
    #pragma unroll
    for (int q = 0; q < 4; q++)
      s0i[q] = perm_s[sB + min(s0 + q * 4 + w, s1 - 1)];
    #pragma unroll
    for (int q = 0; q < 4; q++)
      dma16((const char*)feats + ((size_t)((b << 12) + s0i[q]) << 10) + (size_t)lane * 16,
            (void*)&fL[(q * 4 + w) * 256]);
    #pragma unroll
    for (int q = 0; q < 4; q++)                // indices for round 1's DMA
      sidxN[q] = perm_s[sB + min(s0 + CH + q * 4 + w, s1 - 1)];
  }

  float acc[4][8];
  #pragma unroll
  for (int i = 0; i < 4; i++)
    #pragma unroll
    for (int j = 0; j < 8; j++) acc[i][j] = 0.f;

  int bb = 0;
  for (int n0 = s0; n0 < s1; n0 += CH, bb ^= 1) {
    asm volatile("s_waitcnt vmcnt(0)" ::: "memory");       // own DMA+prefetch done
    __builtin_amdgcn_s_barrier();                          // publish to all waves
    __builtin_amdgcn_sched_barrier(0);
    const int n1 = n0 + CH;
    const bool more = (n1 < s1);                           // uniform
    if (more) {                                            // issue next round
      #pragma unroll
      for (int q = 0; q < 4; q++)
        dma16((const char*)feats + ((size_t)((b << 12) + sidxN[q]) << 10) + (size_t)lane * 16,
              (void*)&fL[((bb ^ 1) * CH + q * 4 + w) * 256]);
      pnA = s_sorted[sB + min(n1 + nnA, s1 - 1)];
      pnB = s_sorted[sB + min(n1 + nnB, s1 - 1)];
      #pragma unroll
      for (int q = 0; q < 4; q++)
        sidxN[q] = perm_s[sB + min(n1 + CH + q * 4 + w, s1 - 1)];
    }
    {                                          // attn(k): 2 wave-local entries
      float dx = t4p.x - psA.x, dy = t4p.y - psA.y;
      float d2 = fmaf(dx, dx, dy * dy);
      bool  c  = (n0 + nnA < s1) && (d2 < T2) && (psA.w != 0.f) && (t4p.w != 0.f);
      attnL[nnA * 36 + tmp_] = c ? __expf(fmaf(d2, -INV_EPS, t4p.z + psA.z)) : 0.f;
      dx = t4p.x - psB.x; dy = t4p.y - psB.y;
      d2 = fmaf(dx, dx, dy * dy);
      c  = (n0 + nnB < s1) && (d2 < T2) && (psB.w != 0.f) && (t4p.w != 0.f);
      attnL[nnB * 36 + tmp_] = c ? __expf(fmaf(d2, -INV_EPS, t4p.z + psB.z)) : 0.f;
    }
    const float* fb = &fL[bb * CH * 256];
    #pragma unroll 4                           // MAC: 3 ds_read_b128 per 32 FMA
    for (int nn = 0; nn < 16; nn++) {
      const float4 av = *(const float4*)&attnL[nn * 36 + tmg * 4];
      const float4 f0 = *(const float4*)&fb[nn * 256 + chg * 4];
      const float4 f1 = *(const float4*)&fb[nn * 256 + 128 + chg * 4];
      float avv[4] = {av.x, av.y, av.z, av.w};
      float ff[8]  = {f0.x, f0.y, f0.z, f0.w, f1.x, f1.y, f1.z, f1.w};
      #pragma unroll
      for (int i = 0; i < 4; i++)
        #pragma unroll
        for (int j = 0; j < 8; j++)
          acc[i][j] = fmaf(avv[i], ff[j], acc[i][j]);
    }
    if (more) { psA = pnA; psB = pnB; }        // rotate s-row prefetch
  }
  #pragma unroll
  for (int i = 0; i < 4; i++) {
    int tm = tmg * 4 + i;
    if (tm < nt) {
      float* op = out + (((b << 12) + morg[tm]) << 8) + chg * 4;
      #pragma unroll
      for (int j = 0; j < 4; j++) atomicAdd(op + j,       acc[i][j]);
      #pragma unroll
      for (int j = 0; j < 4; j++) atomicAdd(op + 128 + j, acc[i][j + 4]);
    }
  }
}

// ----------------------------------------------------------------- launch ---
extern "C" void kernel_launch(void* const* d_in, const int* in_sizes, int n_in,
                              void* d_out, int out_size, void* d_ws, size_t ws_size,
                              hipStream_t stream) {
  const float* feats = (const float*)d_in[0];   // [B,N,C] f32
  const float* slocs = (const float*)d_in[1];   // [B,N,2] f32
  const float* tlocs = (const float*)d_in[2];   // [B,M,2] f32
  const int*   smask = (const int*)d_in[3];     // [B,N] int32 (bool)
  const int*   tmask = (const int*)d_in[4];     // [B,M] int32 (bool)
  float* out = (float*)d_out;

  char* ws = (char*)d_ws;                       // ~660 KB used
  int*    Zc       = (int*)(ws + 1024);         //   256 ints; slot 0 stays 0
  int*    starts_t = (int*)(ws + 2048);         //   512 B
  int*    starts_s = (int*)(ws + 2560);         //   512 B
  int*    perm_t   = (int*)(ws + 4096);         //   64 KB
  int*    perm_s   = (int*)(ws + 69632);        //   64 KB
  float4* s_sorted = (float4*)(ws + 135168);    //  256 KB (x,y,v,sv) cell-sorted
  float4* t_sorted = (float4*)(ws + 397312);    //  256 KB (x,y,u,tv) cell-sorted

  hipMemsetAsync(out, 0, (size_t)out_size * sizeof(float), stream);
  k_bin<<<8, 256, 0, stream>>>(tlocs, slocs, tmask, smask, Zc,
                               starts_t, starts_s, perm_t, perm_s,
                               t_sorted, s_sorted);
  for (int it = 0; it < 3; it++) {
    // u-update: Zin = leak count of current v (slot 0 = zeros for it==0)
    k_sink<<<1024, 256, 0, stream>>>(s_sorted, t_sorted, starts_s,
                                     Zc + (it == 0 ? 0 : (2 * it) * 4),
                                     Zc + (2 * it + 1) * 4, 0);
    // v-update: Zin = leak count of u just written
    k_sink<<<1024, 256, 0, stream>>>(t_sorted, s_sorted, starts_t,
                                     Zc + (2 * it + 1) * 4,
                                     Zc + (2 * it + 2) * 4, 1);
  }
  k_out<<<dim3(MAXCH, 75, BB), 256, 0, stream>>>(feats, t_sorted, s_sorted,
                                                 perm_t, perm_s, starts_t,
                                                 starts_s, out);
}